// Round 5
// baseline (70.938 us; speedup 1.0000x reference)
//
#include <hip/hip_runtime.h>
#include <math.h>

#define CC 8
#define PP 169
#define KTOT 100
#define WW 128
#define HWSZ (128*128)
#define KCH 2           // instances per compute-block chunk (100 = 50 chunks)
#define PXT 8           // pixels per thread
#define FPI 192         // packed floats per instance (768 B)

// packed per-instance layout (FPI floats):
//  [0:80)    w0 (8 x 10) row-major
//  [80:88)   b0
//  [88:152)  w1 (8 x 8) row-major
//  [152:160) b1
//  [160:168) w2
//  [168]     b2
//  [169]     sx   [170] sy   [171:192) pad

__global__ __launch_bounds__(256) void pack_kernel(
    const float* __restrict__ conv_weight,  // (B, P, HW)
    const int*   __restrict__ ind,          // (B, K) flat
    float*       __restrict__ pw)           // (400, FPI)
{
    const int id = blockIdx.x * 256 + threadIdx.x;
    if (id >= 4 * KTOT * FPI) return;
    const int n = id / FPI;
    const int j = id - n * FPI;
    const int b = n / KTOT;
    const int hw = ind[n];
    float v = 0.0f;
    if (j < 169) {
        int p;
        if (j < 80)       p = j;                  // w0
        else if (j < 88)  p = 152 + (j - 80);     // b0
        else if (j < 152) p = 80 + (j - 88);      // w1
        else if (j < 160) p = 160 + (j - 152);    // b1
        else if (j < 168) p = 144 + (j - 160);    // w2
        else              p = 168;                // b2
        v = conv_weight[(size_t)(b * PP + p) * HWSZ + hw];
    } else if (j == 169) {
        v = (float)(hw & (WW - 1));
    } else if (j == 170) {
        v = (float)(hw >> 7);
    }
    pw[id] = v;
}

__global__ __launch_bounds__(256, 4) void condinst_kernel(
    const float* __restrict__ seg_feat,     // (B, C, HW)
    const float* __restrict__ pw,           // (400, FPI) packed params
    float*       __restrict__ out)          // (B, K, HW)
{
    const int tile = blockIdx.x;   // 0..7   (2048 px per block)
    const int b    = blockIdx.y;   // 0..3
    const int k0   = blockIdx.z * KCH;

    const int px0 = tile * (256 * PXT) + threadIdx.x * PXT;

    // ---- per-thread pixel state, loaded once ----
    float ff[CC][PXT];
    #pragma unroll
    for (int c = 0; c < CC; ++c) {
        float4 v0 = *(const float4*)&seg_feat[(size_t)(b * CC + c) * HWSZ + px0];
        float4 v1 = *(const float4*)&seg_feat[(size_t)(b * CC + c) * HWSZ + px0 + 4];
        ff[c][0] = v0.x; ff[c][1] = v0.y; ff[c][2] = v0.z; ff[c][3] = v0.w;
        ff[c][4] = v1.x; ff[c][5] = v1.y; ff[c][6] = v1.z; ff[c][7] = v1.w;
    }
    const float x0 = (float)(px0 & (WW - 1));   // px0 % 8 == 0 -> same row
    const float yp = (float)(px0 >> 7);

    for (int k = 0; k < KCH; ++k) {
        const int inst = b * KTOT + k0 + k;
        const float* __restrict__ p = pw + (size_t)inst * FPI;  // block-uniform -> s_load

        const float rx0 = (p[169] - x0) * 0.0078125f;
        const float ry  = (p[170] - yp) * 0.0078125f;
        float rx[PXT];
        #pragma unroll
        for (int t = 0; t < PXT; ++t) rx[t] = rx0 - (float)t * 0.0078125f;

        // ---- layer 0: 10 -> 8, relu (o-outer, t-inner) ----
        float h0[CC][PXT];
        #pragma unroll
        for (int o = 0; o < CC; ++o) {
            const float wx = p[o * 10 + 0];
            const float wy = p[o * 10 + 1];
            const float w2c = p[o * 10 + 2], w3c = p[o * 10 + 3];
            const float w4c = p[o * 10 + 4], w5c = p[o * 10 + 5];
            const float w6c = p[o * 10 + 6], w7c = p[o * 10 + 7];
            const float w8c = p[o * 10 + 8], w9c = p[o * 10 + 9];
            const float bb = p[80 + o];     // one v_mov per (o,k), amortized over 8 px
            #pragma unroll
            for (int t = 0; t < PXT; ++t) {
                float a = fmaf(wx, rx[t], bb);
                a = fmaf(wy, ry, a);
                a = fmaf(w2c, ff[0][t], a);
                a = fmaf(w3c, ff[1][t], a);
                a = fmaf(w4c, ff[2][t], a);
                a = fmaf(w5c, ff[3][t], a);
                a = fmaf(w6c, ff[4][t], a);
                a = fmaf(w7c, ff[5][t], a);
                a = fmaf(w8c, ff[6][t], a);
                a = fmaf(w9c, ff[7][t], a);
                h0[o][t] = fmaxf(a, 0.0f);
            }
        }

        // ---- layers 1+2, t-outer to cap liveness ----
        float res[PXT];
        #pragma unroll
        for (int t = 0; t < PXT; ++t) {
            float h1[CC];
            #pragma unroll
            for (int o = 0; o < CC; ++o) {
                float a = p[152 + o];
                #pragma unroll
                for (int c = 0; c < CC; ++c)
                    a = fmaf(p[88 + o * 8 + c], h0[c][t], a);
                h1[o] = fmaxf(a, 0.0f);
            }
            float z = p[168];
            #pragma unroll
            for (int c = 0; c < CC; ++c)
                z = fmaf(p[160 + c], h1[c], z);
            res[t] = 1.0f / (1.0f + __expf(-z));
        }

        float* outp = &out[(size_t)inst * HWSZ + px0];
        *(float4*)outp       = make_float4(res[0], res[1], res[2], res[3]);
        *(float4*)(outp + 4) = make_float4(res[4], res[5], res[6], res[7]);
    }
}

extern "C" void kernel_launch(void* const* d_in, const int* in_sizes, int n_in,
                              void* d_out, int out_size, void* d_ws, size_t ws_size,
                              hipStream_t stream) {
    const float* seg_feat    = (const float*)d_in[0];
    const float* conv_weight = (const float*)d_in[1];
    const int*   ind         = (const int*)d_in[2];
    float*       out         = (float*)d_out;
    float*       pw          = (float*)d_ws;   // 400*192*4 = 307200 B

    {
        int total = 4 * KTOT * FPI;
        dim3 grid((total + 255) / 256), block(256);
        pack_kernel<<<grid, block, 0, stream>>>(conv_weight, ind, pw);
    }
    {
        dim3 grid(8, 4, 50), block(256);   // 1600 blocks
        condinst_kernel<<<grid, block, 0, stream>>>(seg_feat, pw, out);
    }
}

// Round 8
// 31.086 us; speedup vs baseline: 2.2820x; 2.2820x over previous
//
#include <hip/hip_runtime.h>
#include <hip/hip_fp16.h>
#include <math.h>

typedef unsigned int u32;
typedef __attribute__((ext_vector_type(8))) _Float16 f16x8;  // 8 fp16 in 4 VGPRs
typedef __attribute__((ext_vector_type(16))) float f32x16;   // 32x32 MFMA acc

#define HW 16384
#define NB 4
#define NK 100
#define NGRP 25   // instance-groups of 4 per batch

// ---------------- helpers ----------------
__device__ __forceinline__ u32 pk2h(float lo, float hi) {    // fp32x2 -> packed fp16 RNE
    return (u32)__half_as_ushort(__float2half_rn(lo))
         | ((u32)__half_as_ushort(__float2half_rn(hi)) << 16);
}
// a' = [a.lo32lanes, b.lo32lanes]; b' = [a.hi32lanes, b.hi32lanes]
__device__ __forceinline__ void swap32(u32 &a, u32 &b) {
    asm("v_permlane32_swap_b32 %0, %1" : "+v"(a), "+v"(b));
}
__device__ __forceinline__ float rcpf(float x) {
    float r; asm("v_rcp_f32 %0, %1" : "=v"(r) : "v"(x)); return r;
}

// ---------------- pack: gather conv_weight -> MFMA fragment layouts (fp16) ----------------
// A0: 100 (b,g)-groups x 64 lanes x 4 u32 (fp16 pairs)   -> 102400 B
//     A(32x16): row = lane&31 = inst_local*8+ch_out, k = 8*(lane>>5)+2*reg+j
//     k=0: -wx/128, k=1: -wy/128, k=2..9: w0[ch][k], k=10: b0 + (wx*sx+wy*sy)/128, k>=11: 0
// A1: 100 groups x 2 frags x 64 lanes x 4 u32            -> 204800 B  (block-diag W1)
// WT: 100 groups x 80 f32 (320 B):
//     [0:16)  d1-init (b1) for lo lanes: e -> b1[row], row=(e&3)+8*(e>>2)
//     [16:32) d1-init (b1) for hi lanes: row=(e&3)+8*(e>>2)+4
//     [32:48) w2 lo-half: n=(q>>2), j=q&3 -> w2[n][j]
//     [48:64) w2 hi-half: w2[n][4+j]
//     [64:68) 0.5*b2[n]
//     [68:80) pad
__global__ __launch_bounds__(256) void pack_kernel(
    const float* __restrict__ cw, const int* __restrict__ ind,
    u32* __restrict__ A0, u32* __restrict__ A1, float* __restrict__ WT)
{
    int id = blockIdx.x * 256 + threadIdx.x;
    if (id < 25600) {                       // ---- A0 ----
        int bg = id >> 8, rem = id & 255;
        int lane = rem >> 2, reg = rem & 3;
        int b = bg / NGRP, g = bg % NGRP;
        int row = lane & 31;
        int inst = g * 4 + (row >> 3);
        int ch = row & 7;
        int hw = ind[b * NK + inst];
        const float* base = cw + (size_t)b * 169 * HW + hw;
        float sx = (float)(hw & 127), sy = (float)(hw >> 7);
        float v[2];
        #pragma unroll
        for (int j = 0; j < 2; ++j) {
            int k = ((lane >> 5) << 3) + reg * 2 + j;
            float val = 0.f;
            if (k < 2)
                val = -base[(size_t)(ch * 10 + k) * HW] * 0.0078125f;
            else if (k < 10)
                val = base[(size_t)(ch * 10 + k) * HW];
            else if (k == 10)
                val = base[(size_t)(152 + ch) * HW]
                    + (base[(size_t)(ch * 10) * HW] * sx
                     + base[(size_t)(ch * 10 + 1) * HW] * sy) * 0.0078125f;
            v[j] = val;
        }
        A0[id] = pk2h(v[0], v[1]);
    } else if (id < 76800) {                // ---- A1 (block-diagonal W1) ----
        int id2 = id - 25600;
        int bg = id2 >> 9, r2 = id2 & 511;
        int frag = r2 >> 8;
        int lane = (r2 >> 2) & 63, reg = r2 & 3;
        int b = bg / NGRP, g = bg % NGRP;
        int row = lane & 31;
        int inst = g * 4 + (row >> 3);
        int hw = ind[b * NK + inst];
        const float* base = cw + (size_t)b * 169 * HW + hw;
        float v[2];
        #pragma unroll
        for (int j = 0; j < 2; ++j) {
            int k = ((lane >> 5) << 3) + reg * 2 + j;
            bool valid = ((row >> 4) == frag) && (((row >> 3) & 1) == (k >> 3));
            v[j] = valid ? base[(size_t)(80 + (row & 7) * 8 + (k & 7)) * HW] : 0.f;
        }
        A1[id2] = pk2h(v[0], v[1]);
    } else if (id < 84800) {                // ---- WT (fp32 tables) ----
        int id3 = id - 76800;
        int bg = id3 / 80, q = id3 - bg * 80;
        int b = bg / NGRP, g = bg % NGRP;
        float val = 0.f;
        if (q < 32) {                       // d1-init = b1[row]
            int hi = q >> 4, e = q & 15;
            int row = (e & 3) + 8 * (e >> 2) + 4 * hi;
            int inst = g * 4 + (row >> 3);
            int hw = ind[b * NK + inst];
            val = cw[(size_t)b * 169 * HW + (size_t)(160 + (row & 7)) * HW + hw];
        } else if (q < 64) {                // w2 halves
            int half = (q - 32) >> 4, q2 = (q - 32) & 15;
            int n = q2 >> 2, j = q2 & 3;
            int hw = ind[b * NK + g * 4 + n];
            val = cw[(size_t)b * 169 * HW + (size_t)(144 + half * 4 + j) * HW + hw];
        } else if (q < 68) {                // 0.5*b2
            int n = q - 64;
            int hw = ind[b * NK + g * 4 + n];
            val = 0.5f * cw[(size_t)b * 169 * HW + (size_t)168 * HW + hw];
        }
        WT[id3] = val;
    }
}

// ---------------- compute: 3-layer MLP via fp16 MFMA, 32 px x 4 inst per wave-step ----------------
__global__ __launch_bounds__(64, 4) void mfma_kernel(
    const float* __restrict__ seg_feat,
    const u32* __restrict__ A0, const u32* __restrict__ A1,
    const float* __restrict__ WT, float* __restrict__ out)
{
    const int lane = threadIdx.x;           // 0..63
    const bool hi = lane >= 32;
    const int col = lane & 31;              // pixel column within tile
    const int tile = blockIdx.x;            // 0..511
    const int b = blockIdx.y;               // 0..3
    const int g0 = blockIdx.z * 13;
    const int g1 = blockIdx.z ? NGRP : 13;

    const int px = tile * 32 + col;

    // B0 fragment (K=16 x N=32 px): k = 8*(lane>=32)+j = [xp,yp,f0..f5 | f6,f7,1,0...]
    float f[8];
    #pragma unroll
    for (int c = 0; c < 8; ++c)
        f[c] = seg_feat[(size_t)(b * 8 + c) * HW + px];
    const float xp = (float)(px & 127), yp = (float)(px >> 7);

    u32 b0w0 = hi ? pk2h(f[6], f[7]) : pk2h(xp, yp);
    u32 b0w1 = hi ? 0x00003C00u : pk2h(f[0], f[1]);   // (fp16 1.0, 0) : (f0, f1)
    u32 b0w2 = hi ? 0u : pk2h(f[2], f[3]);
    u32 b0w3 = hi ? 0u : pk2h(f[4], f[5]);
    uint4 b0u = make_uint4(b0w0, b0w1, b0w2, b0w3);
    f16x8 B0 = __builtin_bit_cast(f16x8, b0u);

    f32x16 zero;
    #pragma unroll
    for (int i = 0; i < 16; ++i) zero[i] = 0.f;

    for (int g = g0; g < g1; ++g) {
        const int bg = b * NGRP + g;
        uint4 a0w  = ((const uint4*)A0)[bg * 64 + lane];
        uint4 a1aw = ((const uint4*)A1)[(bg * 2 + 0) * 64 + lane];
        uint4 a1bw = ((const uint4*)A1)[(bg * 2 + 1) * 64 + lane];
        const float* wb = WT + bg * 80;
        const float4* bi = (const float4*)(wb + (hi ? 16 : 0));
        float4 i0 = bi[0], i1 = bi[1], i2 = bi[2], i3 = bi[3];
        const float4* wv = (const float4*)(wb + 32 + (hi ? 16 : 0));
        float4 wn0 = wv[0], wn1 = wv[1], wn2 = wv[2], wn3 = wv[3];

        // layer 0: D0(32ch x 32px), row = (r&3)+8*(r>>2)+4*hi
        f32x16 d0 = __builtin_amdgcn_mfma_f32_32x32x16_f16(
            __builtin_bit_cast(f16x8, a0w), B0, zero, 0, 0, 0);

        // relu + fp16-pack (RNE) + cross-half swap -> B1 fragments
        u32 u0 = pk2h(fmaxf(d0[0], 0.f),  fmaxf(d0[1], 0.f));   // rows 0,1 / 4,5
        u32 u1 = pk2h(fmaxf(d0[2], 0.f),  fmaxf(d0[3], 0.f));   // rows 2,3 / 6,7
        u32 u2 = pk2h(fmaxf(d0[4], 0.f),  fmaxf(d0[5], 0.f));   // rows 8,9 / 12,13
        u32 u3 = pk2h(fmaxf(d0[6], 0.f),  fmaxf(d0[7], 0.f));   // rows 10,11 / 14,15
        u32 u4 = pk2h(fmaxf(d0[8], 0.f),  fmaxf(d0[9], 0.f));   // rows 16,17 / 20,21
        u32 u5 = pk2h(fmaxf(d0[10], 0.f), fmaxf(d0[11], 0.f));  // rows 18,19 / 22,23
        u32 u6 = pk2h(fmaxf(d0[12], 0.f), fmaxf(d0[13], 0.f));  // rows 24,25 / 28,29
        u32 u7 = pk2h(fmaxf(d0[14], 0.f), fmaxf(d0[15], 0.f));  // rows 26,27 / 30,31
        swap32(u0, u2);   // u0 -> B1a word0 (k 0,1 / 8,9), u2 -> word2 (k 4,5 / 12,13)
        swap32(u1, u3);   // u1 -> word1, u3 -> word3
        swap32(u4, u6);   // B1b likewise (rows 16..31)
        swap32(u5, u7);
        uint4 b1au = make_uint4(u0, u1, u2, u3);
        uint4 b1bu = make_uint4(u4, u5, u6, u7);

        // layer 1: two K=16 MFMAs over block-diag W1, acc seeded with b1
        f32x16 d1;
        d1[0] = i0.x; d1[1] = i0.y; d1[2]  = i0.z; d1[3]  = i0.w;
        d1[4] = i1.x; d1[5] = i1.y; d1[6]  = i1.z; d1[7]  = i1.w;
        d1[8] = i2.x; d1[9] = i2.y; d1[10] = i2.z; d1[11] = i2.w;
        d1[12] = i3.x; d1[13] = i3.y; d1[14] = i3.z; d1[15] = i3.w;
        d1 = __builtin_amdgcn_mfma_f32_32x32x16_f16(
            __builtin_bit_cast(f16x8, a1aw), __builtin_bit_cast(f16x8, b1au), d1, 0, 0, 0);
        d1 = __builtin_amdgcn_mfma_f32_32x32x16_f16(
            __builtin_bit_cast(f16x8, a1bw), __builtin_bit_cast(f16x8, b1bu), d1, 0, 0, 0);

        // layer 2: per-lane 4-ch partial dot (fp32), cross-half reduce, sigmoid
        const float b2h0 = wb[64], b2h1 = wb[65], b2h2 = wb[66], b2h3 = wb[67];

        float pz0 = b2h0, pz1 = b2h1, pz2 = b2h2, pz3 = b2h3;
        pz0 = fmaf(wn0.x, fmaxf(d1[0], 0.f), pz0);
        pz0 = fmaf(wn0.y, fmaxf(d1[1], 0.f), pz0);
        pz0 = fmaf(wn0.z, fmaxf(d1[2], 0.f), pz0);
        pz0 = fmaf(wn0.w, fmaxf(d1[3], 0.f), pz0);
        pz1 = fmaf(wn1.x, fmaxf(d1[4], 0.f), pz1);
        pz1 = fmaf(wn1.y, fmaxf(d1[5], 0.f), pz1);
        pz1 = fmaf(wn1.z, fmaxf(d1[6], 0.f), pz1);
        pz1 = fmaf(wn1.w, fmaxf(d1[7], 0.f), pz1);
        pz2 = fmaf(wn2.x, fmaxf(d1[8], 0.f), pz2);
        pz2 = fmaf(wn2.y, fmaxf(d1[9], 0.f), pz2);
        pz2 = fmaf(wn2.z, fmaxf(d1[10], 0.f), pz2);
        pz2 = fmaf(wn2.w, fmaxf(d1[11], 0.f), pz2);
        pz3 = fmaf(wn3.x, fmaxf(d1[12], 0.f), pz3);
        pz3 = fmaf(wn3.y, fmaxf(d1[13], 0.f), pz3);
        pz3 = fmaf(wn3.z, fmaxf(d1[14], 0.f), pz3);
        pz3 = fmaf(wn3.w, fmaxf(d1[15], 0.f), pz3);

        u32 a01 = __builtin_bit_cast(u32, pz0), b01 = __builtin_bit_cast(u32, pz1);
        swap32(a01, b01);   // lanes<32: both halves of inst0; lanes>=32: inst1
        float z01 = __builtin_bit_cast(float, a01) + __builtin_bit_cast(float, b01);
        u32 a23 = __builtin_bit_cast(u32, pz2), b23 = __builtin_bit_cast(u32, pz3);
        swap32(a23, b23);
        float z23 = __builtin_bit_cast(float, a23) + __builtin_bit_cast(float, b23);

        float o01 = rcpf(1.f + __expf(-z01));
        float o23 = rcpf(1.f + __expf(-z23));

        size_t obase = (size_t)(b * NK + g * 4) * HW + px;
        out[obase + (size_t)(hi ? 1 : 0) * HW] = o01;
        out[obase + (size_t)(hi ? 3 : 2) * HW] = o23;
    }
}

extern "C" void kernel_launch(void* const* d_in, const int* in_sizes, int n_in,
                              void* d_out, int out_size, void* d_ws, size_t ws_size,
                              hipStream_t stream) {
    const float* seg_feat    = (const float*)d_in[0];
    const float* conv_weight = (const float*)d_in[1];
    const int*   ind         = (const int*)d_in[2];
    float*       out         = (float*)d_out;

    u32*   A0 = (u32*)d_ws;                                 // 102400 B
    u32*   A1 = (u32*)((char*)d_ws + 102400);               // 204800 B
    float* WT = (float*)((char*)d_ws + 307200);             // 32000 B

    {
        dim3 grid((84800 + 255) / 256), block(256);
        pack_kernel<<<grid, block, 0, stream>>>(conv_weight, ind, A0, A1, WT);
    }
    {
        dim3 grid(512, 4, 2), block(64);    // 4096 single-wave blocks = 16 waves/CU
        mfma_kernel<<<grid, block, 0, stream>>>(seg_feat, A0, A1, WT, out);
    }
}